// Round 10
// baseline (256.402 us; speedup 1.0000x reference)
//
#include <hip/hip_runtime.h>
#include <math.h>

#define TOKENS 16384
#define DMODEL 2048
#define NEXP   64
#define TOPK   8
#define WSHORTS 12288        // shorts per 64-k chunk W image (24 frags x 1024 B)

typedef unsigned short u16;
typedef float f32x4 __attribute__((ext_vector_type(4)));
typedef short s16x8 __attribute__((ext_vector_type(8)));

// RNE fp32 -> bf16, also returning the rounded-back fp32 value.
// (bit-identical to the passing R1/R2/R7 kernels' split -> identical logits)
__device__ __forceinline__ u16 f2bf(float f, float& back) {
    unsigned u = __float_as_uint(f);
    unsigned r = u + 0x7fffu + ((u >> 16) & 1u);
    back = __uint_as_float(r & 0xffff0000u);
    return (u16)(r >> 16);
}

// Kernel 1 (unchanged from passing R2/R7): pre-split W into 3 bf16 terms in
// MFMA B-FRAGMENT ORDER: chunk c -> 24 fragments of 1024B, frag(tau,ks,eq) at
// ((tau*2+ks)*4+eq), lane l's 16B = expert eq*16+(l&15), k = c*64+ks*32+(l>>4)*8.
__global__ __launch_bounds__(256) void wconv(
    const float* __restrict__ W, u16* __restrict__ wimg)
{
    const int id  = blockIdx.x * 256 + threadIdx.x;  // 16384 threads
    const int e   = id >> 8;     // expert 0..63
    const int ko8 = id & 255;    // k-oct 0..255
    const int k0  = ko8 * 8;
    const int c   = ko8 >> 3;          // chunk
    const int ks  = (ko8 >> 2) & 1;    // k-half within chunk
    const int hi  = ko8 & 3;           // lane>>4 part
    const int lane = hi * 16 + (e & 15);
    const int eq   = e >> 4;

    const float* src = W + (size_t)e * DMODEL + k0;
    const float4 f0 = *(const float4*)(src);
    const float4 f1 = *(const float4*)(src + 4);
    const float xe[8] = {f0.x, f0.y, f0.z, f0.w, f1.x, f1.y, f1.z, f1.w};
    s16x8 va, vb, vc;
#pragma unroll
    for (int j = 0; j < 8; ++j) {
        float b1, b2, b3;
        const u16 a1 = f2bf(xe[j], b1);
        const float d1 = xe[j] - b1;   // exact (Sterbenz)
        const u16 a2 = f2bf(d1, b2);
        const float d2 = d1 - b2;      // exact
        const u16 a3 = f2bf(d2, b3);
        va[j] = (short)a1; vb[j] = (short)a2; vc[j] = (short)a3;
    }
    u16* base = wimg + (size_t)c * WSHORTS + lane * 8;
    *(s16x8*)(base + ((0 * 2 + ks) * 4 + eq) * 512) = va;
    *(s16x8*)(base + ((1 * 2 + ks) * 4 + eq) * 512) = vb;
    *(s16x8*)(base + ((2 * 2 + ks) * 4 + eq) * 512) = vc;
}

// Kernel 2: fused router with 2x B-REUSE per wave.
//  R7 diagnosis: R2 (lockstep) and R7 (barrier-free) both ~113us -> shared
//  bottleneck = B-fragment traffic: 786 MB pulled from the same 768KB of L2
//  lines at a sustained 6.8 TB/s (channel-contended ceiling). Fix: each wave
//  now covers 32 tokens (two 16-token subgroups) per 12-fragment B load ->
//  B L2 traffic halves to 393 MB, loads-per-MFMA halves, and subgroup 1's
//  split/MFMA overlaps subgroup 0's load latency (ILP). Register budget
//  (~190 VGPR) deliberately exceeds the 64-VGPR minimal-schedule regime the
//  compiler chose in R2/R7.
//  Numerics: per-token op sequence (f2bf split values, 6-MFMA chain order,
//  per-64k fp64 flush) BIT-IDENTICAL to the passing R7 kernel.
__global__ __launch_bounds__(256) void router_fused(
    const float* __restrict__ x, const u16* __restrict__ wimg,
    const float* __restrict__ bias, float* __restrict__ out_w,
    float* __restrict__ out_i)
{
    __shared__ double lg[2][32][NEXP];   // 32768 B, epilogue only

    const int tid  = threadIdx.x;
    const int lane = tid & 63;
    const int w    = tid >> 6;   // wave 0..3
    const int eh   = w & 1;      // expert half (32 cols)
    const int kh   = w >> 1;     // k half (1024)
    const size_t tokBase = (size_t)blockIdx.x * 32;

    // A-side: lane owns token (lane&15) of each 16-token subgroup, k-oct lane>>4
    const int arow = lane & 15;
    const float* xrow0 = x + (tokBase + arow) * (size_t)DMODEL + kh * 1024 +
                         (lane >> 4) * 8;
    const float* xrow1 = xrow0 + (size_t)16 * DMODEL;
    // B-side: frag(tau,ks,nt) at wt + ((tau*2+ks)*4 + nt)*512 shorts
    const u16* wt0 = wimg + (size_t)kh * 16 * WSHORTS +
                     (size_t)(eh * 2) * 512 + lane * 8;

    f32x4  acc0[2][2], acc1[2][2];   // [ks][nt] per token-subgroup
    double accd0[2][4], accd1[2][4]; // [nt][reg]
#pragma unroll
    for (int i = 0; i < 2; ++i)
#pragma unroll
        for (int j = 0; j < 2; ++j) {
            acc0[i][j] = (f32x4){0.f, 0.f, 0.f, 0.f};
            acc1[i][j] = (f32x4){0.f, 0.f, 0.f, 0.f};
        }
#pragma unroll
    for (int j = 0; j < 2; ++j)
#pragma unroll
        for (int r = 0; r < 4; ++r) { accd0[j][r] = 0.0; accd1[j][r] = 0.0; }

    // prologue: x chunk 0, both subgroups
    float4 xv0[4], xv1[4];
    xv0[0] = *(const float4*)(xrow0);      xv0[1] = *(const float4*)(xrow0 + 4);
    xv0[2] = *(const float4*)(xrow0 + 32); xv0[3] = *(const float4*)(xrow0 + 36);
    xv1[0] = *(const float4*)(xrow1);      xv1[1] = *(const float4*)(xrow1 + 4);
    xv1[2] = *(const float4*)(xrow1 + 32); xv1[3] = *(const float4*)(xrow1 + 36);

    for (int t = 0; t < 16; ++t) {
        const u16* wt = wt0 + (size_t)t * WSHORTS;
        // issue all 12 B loads for this chunk; the tg0 split below is pure
        // VALU and overlaps their latency
        s16x8 b[3][2][2];   // [tau][ks][nt]
#pragma unroll
        for (int tau = 0; tau < 3; ++tau)
#pragma unroll
            for (int ks = 0; ks < 2; ++ks)
#pragma unroll
                for (int nt = 0; nt < 2; ++nt)
                    b[tau][ks][nt] = *(const s16x8*)(
                        wt + ((tau * 2 + ks) * 4 + nt) * 512);

        // ---------- token subgroup 0 ----------
        s16x8 af[3][2];
#pragma unroll
        for (int ks = 0; ks < 2; ++ks) {
            const float xe[8] = {xv0[ks * 2].x,     xv0[ks * 2].y,
                                 xv0[ks * 2].z,     xv0[ks * 2].w,
                                 xv0[ks * 2 + 1].x, xv0[ks * 2 + 1].y,
                                 xv0[ks * 2 + 1].z, xv0[ks * 2 + 1].w};
#pragma unroll
            for (int j = 0; j < 8; ++j) {
                float b1, b2, b3;
                const u16 a1 = f2bf(xe[j], b1);
                const float d1 = xe[j] - b1;
                const u16 a2 = f2bf(d1, b2);
                const float d2 = d1 - b2;
                const u16 a3 = f2bf(d2, b3);
                af[0][ks][j] = (short)a1;
                af[1][ks][j] = (short)a2;
                af[2][ks][j] = (short)a3;
            }
        }
        if (t + 1 < 16) {   // xv0 dead: prefetch next chunk (full-chunk window)
            const float* xp = xrow0 + (size_t)(t + 1) * 64;
            xv0[0] = *(const float4*)(xp);      xv0[1] = *(const float4*)(xp + 4);
            xv0[2] = *(const float4*)(xp + 32); xv0[3] = *(const float4*)(xp + 36);
        }
#pragma unroll
        for (int ks = 0; ks < 2; ++ks)
#pragma unroll
            for (int nt = 0; nt < 2; ++nt) {
                f32x4 t0 = acc0[ks][nt];
                t0 = __builtin_amdgcn_mfma_f32_16x16x32_bf16(af[0][ks], b[0][ks][nt], t0, 0, 0, 0);
                t0 = __builtin_amdgcn_mfma_f32_16x16x32_bf16(af[0][ks], b[1][ks][nt], t0, 0, 0, 0);
                t0 = __builtin_amdgcn_mfma_f32_16x16x32_bf16(af[1][ks], b[0][ks][nt], t0, 0, 0, 0);
                t0 = __builtin_amdgcn_mfma_f32_16x16x32_bf16(af[0][ks], b[2][ks][nt], t0, 0, 0, 0);
                t0 = __builtin_amdgcn_mfma_f32_16x16x32_bf16(af[2][ks], b[0][ks][nt], t0, 0, 0, 0);
                t0 = __builtin_amdgcn_mfma_f32_16x16x32_bf16(af[1][ks], b[1][ks][nt], t0, 0, 0, 0);
                acc0[ks][nt] = t0;
            }

        // ---------- token subgroup 1 (reuses the SAME b frags) ----------
#pragma unroll
        for (int ks = 0; ks < 2; ++ks) {
            const float xe[8] = {xv1[ks * 2].x,     xv1[ks * 2].y,
                                 xv1[ks * 2].z,     xv1[ks * 2].w,
                                 xv1[ks * 2 + 1].x, xv1[ks * 2 + 1].y,
                                 xv1[ks * 2 + 1].z, xv1[ks * 2 + 1].w};
#pragma unroll
            for (int j = 0; j < 8; ++j) {
                float b1, b2, b3;
                const u16 a1 = f2bf(xe[j], b1);
                const float d1 = xe[j] - b1;
                const u16 a2 = f2bf(d1, b2);
                const float d2 = d1 - b2;
                const u16 a3 = f2bf(d2, b3);
                af[0][ks][j] = (short)a1;
                af[1][ks][j] = (short)a2;
                af[2][ks][j] = (short)a3;
            }
        }
        if (t + 1 < 16) {
            const float* xp = xrow1 + (size_t)(t + 1) * 64;
            xv1[0] = *(const float4*)(xp);      xv1[1] = *(const float4*)(xp + 4);
            xv1[2] = *(const float4*)(xp + 32); xv1[3] = *(const float4*)(xp + 36);
        }
#pragma unroll
        for (int ks = 0; ks < 2; ++ks)
#pragma unroll
            for (int nt = 0; nt < 2; ++nt) {
                f32x4 t0 = acc1[ks][nt];
                t0 = __builtin_amdgcn_mfma_f32_16x16x32_bf16(af[0][ks], b[0][ks][nt], t0, 0, 0, 0);
                t0 = __builtin_amdgcn_mfma_f32_16x16x32_bf16(af[0][ks], b[1][ks][nt], t0, 0, 0, 0);
                t0 = __builtin_amdgcn_mfma_f32_16x16x32_bf16(af[1][ks], b[0][ks][nt], t0, 0, 0, 0);
                t0 = __builtin_amdgcn_mfma_f32_16x16x32_bf16(af[0][ks], b[2][ks][nt], t0, 0, 0, 0);
                t0 = __builtin_amdgcn_mfma_f32_16x16x32_bf16(af[2][ks], b[0][ks][nt], t0, 0, 0, 0);
                t0 = __builtin_amdgcn_mfma_f32_16x16x32_bf16(af[1][ks], b[1][ks][nt], t0, 0, 0, 0);
                acc1[ks][nt] = t0;
            }

        // fp64 flush once per 64-k chunk, both subgroups (identical per token)
#pragma unroll
        for (int nt = 0; nt < 2; ++nt)
#pragma unroll
            for (int r = 0; r < 4; ++r) {
                accd0[nt][r] += (double)acc0[0][nt][r] + (double)acc0[1][nt][r];
                acc0[0][nt][r] = 0.f;
                acc0[1][nt][r] = 0.f;
                accd1[nt][r] += (double)acc1[0][nt][r] + (double)acc1[1][nt][r];
                acc1[0][nt][r] = 0.f;
                acc1[1][nt][r] = 0.f;
            }
    }

    // epilogue: k-half exchange (ONE barrier in the whole kernel)
    // C/D mapping (m89): token row = (lane>>4)*4 + r, expert col = lane&15
#pragma unroll
    for (int nt = 0; nt < 2; ++nt)
#pragma unroll
        for (int r = 0; r < 4; ++r) {
            const int row = (lane >> 4) * 4 + r;
            const int col = eh * 32 + nt * 16 + (lane & 15);
            lg[kh][row][col]      = accd0[nt][r];
            lg[kh][row + 16][col] = accd1[nt][r];
        }
    __syncthreads();

    // fused top-8: wave handles 8 tokens, lane = expert (verified epilogue)
    const float be = bias[lane];
#pragma unroll
    for (int i = 0; i < 8; ++i) {
        const int tl = w * 8 + i;
        float v = (float)(lg[0][tl][lane] + lg[1][tl][lane]) + be;
        const int myi = lane;
        float bv = 0.0f; int bi = 0;
#pragma unroll
        for (int r = 0; r < TOPK; ++r) {
            float mv = v; int mi = myi;
#pragma unroll
            for (int off = 32; off > 0; off >>= 1) {
                const float ov = __shfl_xor(mv, off, 64);
                const int   oi = __shfl_xor(mi, off, 64);
                if (ov > mv || (ov == mv && oi < mi)) { mv = ov; mi = oi; }
            }
            if (lane == r) { bv = mv; bi = mi; }
            if (myi == mi) { v = -INFINITY; }
        }
        if (lane < TOPK) {
            const size_t tok = tokBase + tl;
            out_w[tok * TOPK + lane] = 1.0f / (1.0f + expf(-bv));
            out_i[tok * TOPK + lane] = (float)bi;
        }
    }
}

extern "C" void kernel_launch(void* const* d_in, const int* in_sizes, int n_in,
                              void* d_out, int out_size, void* d_ws, size_t ws_size,
                              hipStream_t stream) {
    const float* x    = (const float*)d_in[0];   // [4,4096,2048]
    const float* W    = (const float*)d_in[1];   // [64,2048]
    const float* bias = (const float*)d_in[2];   // [64]
    float* out_w = (float*)d_out;                          // [16384,8]
    float* out_i = (float*)d_out + (size_t)TOKENS * TOPK;  // [16384,8] as float
    u16* wimg = (u16*)d_ws;  // 32 * 24576 B = 786432 B, fragment-ordered

    wconv<<<dim3((NEXP * DMODEL / 8) / 256), 256, 0, stream>>>(W, wimg);
    router_fused<<<dim3(TOKENS / 32), 256, 0, stream>>>(x, wimg, bias, out_w, out_i);
}

// Round 11
// 255.700 us; speedup vs baseline: 1.0027x; 1.0027x over previous
//
#include <hip/hip_runtime.h>
#include <math.h>

#define TOKENS 16384
#define DMODEL 2048
#define NEXP   64
#define TOPK   8
#define WSHORTS 12288        // shorts per 64-k chunk W image (24 frags x 1024 B)

typedef unsigned short u16;
typedef float f32x4 __attribute__((ext_vector_type(4)));
typedef short s16x8 __attribute__((ext_vector_type(8)));

// RNE fp32 -> bf16, also returning the rounded-back fp32 value.
// (bit-identical to the passing R1/R2/R7/R10 kernels' split)
__device__ __forceinline__ u16 f2bf(float f, float& back) {
    unsigned u = __float_as_uint(f);
    unsigned r = u + 0x7fffu + ((u >> 16) & 1u);
    back = __uint_as_float(r & 0xffff0000u);
    return (u16)(r >> 16);
}

// Kernel 1 (unchanged from passing R2/R7/R10): pre-split W into 3 bf16 terms
// in MFMA B-FRAGMENT ORDER: chunk c -> 24 fragments of 1024B, frag(tau,ks,eq)
// at ((tau*2+ks)*4+eq), lane l's 16B = expert eq*16+(l&15), k=c*64+ks*32+(l>>4)*8.
__global__ __launch_bounds__(256) void wconv(
    const float* __restrict__ W, u16* __restrict__ wimg)
{
    const int id  = blockIdx.x * 256 + threadIdx.x;  // 16384 threads
    const int e   = id >> 8;     // expert 0..63
    const int ko8 = id & 255;    // k-oct 0..255
    const int k0  = ko8 * 8;
    const int c   = ko8 >> 3;          // chunk
    const int ks  = (ko8 >> 2) & 1;    // k-half within chunk
    const int hi  = ko8 & 3;           // lane>>4 part
    const int lane = hi * 16 + (e & 15);
    const int eq   = e >> 4;

    const float* src = W + (size_t)e * DMODEL + k0;
    const float4 f0 = *(const float4*)(src);
    const float4 f1 = *(const float4*)(src + 4);
    const float xe[8] = {f0.x, f0.y, f0.z, f0.w, f1.x, f1.y, f1.z, f1.w};
    s16x8 va, vb, vc;
#pragma unroll
    for (int j = 0; j < 8; ++j) {
        float b1, b2, b3;
        const u16 a1 = f2bf(xe[j], b1);
        const float d1 = xe[j] - b1;   // exact (Sterbenz)
        const u16 a2 = f2bf(d1, b2);
        const float d2 = d1 - b2;      // exact
        const u16 a3 = f2bf(d2, b3);
        va[j] = (short)a1; vb[j] = (short)a2; vc[j] = (short)a3;
    }
    u16* base = wimg + (size_t)c * WSHORTS + lane * 8;
    *(s16x8*)(base + ((0 * 2 + ks) * 4 + eq) * 512) = va;
    *(s16x8*)(base + ((1 * 2 + ks) * 4 + eq) * 512) = vb;
    *(s16x8*)(base + ((2 * 2 + ks) * 4 + eq) * 512) = vc;
}

// Kernel 2: R10's 2x-B-reuse kernel with ONE change: #pragma unroll 1 on the
// chunk loop.
//  R10 post-mortem: R2/R7/R10 (three different data-path structures) all
//  ~113us; R7(4 waves/SIMD) == R10(2 waves/SIMD, 2x work/wave) -> zero TLP
//  overlap -> waves serialize on a SHARED resource. Theory: the fully
//  unrolled 16-chunk loop (~50-80KB straight-line code) thrashes the 32KB
//  L1I; all waves stall on instruction fetch from L2 (explains VALUBusy 34%,
//  MfmaUtil 9%, HBM 8% all idle). R0's fast 78us gemm had a small
//  runtime-trip loop body that FITS I$. Fix: unroll 1 -> ~6KB body.
//  Numerics: pragma changes no values -> absmax bit-identical.
__global__ __launch_bounds__(256) void router_fused(
    const float* __restrict__ x, const u16* __restrict__ wimg,
    const float* __restrict__ bias, float* __restrict__ out_w,
    float* __restrict__ out_i)
{
    __shared__ double lg[2][32][NEXP];   // 32768 B, epilogue only

    const int tid  = threadIdx.x;
    const int lane = tid & 63;
    const int w    = tid >> 6;   // wave 0..3
    const int eh   = w & 1;      // expert half (32 cols)
    const int kh   = w >> 1;     // k half (1024)
    const size_t tokBase = (size_t)blockIdx.x * 32;

    // A-side: lane owns token (lane&15) of each 16-token subgroup, k-oct lane>>4
    const int arow = lane & 15;
    const float* xrow0 = x + (tokBase + arow) * (size_t)DMODEL + kh * 1024 +
                         (lane >> 4) * 8;
    const float* xrow1 = xrow0 + (size_t)16 * DMODEL;
    // B-side: frag(tau,ks,nt) at wt + ((tau*2+ks)*4 + nt)*512 shorts
    const u16* wt0 = wimg + (size_t)kh * 16 * WSHORTS +
                     (size_t)(eh * 2) * 512 + lane * 8;

    f32x4  acc0[2][2], acc1[2][2];   // [ks][nt] per token-subgroup
    double accd0[2][4], accd1[2][4]; // [nt][reg]
#pragma unroll
    for (int i = 0; i < 2; ++i)
#pragma unroll
        for (int j = 0; j < 2; ++j) {
            acc0[i][j] = (f32x4){0.f, 0.f, 0.f, 0.f};
            acc1[i][j] = (f32x4){0.f, 0.f, 0.f, 0.f};
        }
#pragma unroll
    for (int j = 0; j < 2; ++j)
#pragma unroll
        for (int r = 0; r < 4; ++r) { accd0[j][r] = 0.0; accd1[j][r] = 0.0; }

    // prologue: x chunk 0, both subgroups
    float4 xv0[4], xv1[4];
    xv0[0] = *(const float4*)(xrow0);      xv0[1] = *(const float4*)(xrow0 + 4);
    xv0[2] = *(const float4*)(xrow0 + 32); xv0[3] = *(const float4*)(xrow0 + 36);
    xv1[0] = *(const float4*)(xrow1);      xv1[1] = *(const float4*)(xrow1 + 4);
    xv1[2] = *(const float4*)(xrow1 + 32); xv1[3] = *(const float4*)(xrow1 + 36);

#pragma unroll 1   // <-- the change under test: keep loop body inside L1I
    for (int t = 0; t < 16; ++t) {
        const u16* wt = wt0 + (size_t)t * WSHORTS;
        // issue all 12 B loads for this chunk; the tg0 split below is pure
        // VALU and overlaps their latency
        s16x8 b[3][2][2];   // [tau][ks][nt]
#pragma unroll
        for (int tau = 0; tau < 3; ++tau)
#pragma unroll
            for (int ks = 0; ks < 2; ++ks)
#pragma unroll
                for (int nt = 0; nt < 2; ++nt)
                    b[tau][ks][nt] = *(const s16x8*)(
                        wt + ((tau * 2 + ks) * 4 + nt) * 512);

        // ---------- token subgroup 0 ----------
        s16x8 af[3][2];
#pragma unroll
        for (int ks = 0; ks < 2; ++ks) {
            const float xe[8] = {xv0[ks * 2].x,     xv0[ks * 2].y,
                                 xv0[ks * 2].z,     xv0[ks * 2].w,
                                 xv0[ks * 2 + 1].x, xv0[ks * 2 + 1].y,
                                 xv0[ks * 2 + 1].z, xv0[ks * 2 + 1].w};
#pragma unroll
            for (int j = 0; j < 8; ++j) {
                float b1, b2, b3;
                const u16 a1 = f2bf(xe[j], b1);
                const float d1 = xe[j] - b1;
                const u16 a2 = f2bf(d1, b2);
                const float d2 = d1 - b2;
                const u16 a3 = f2bf(d2, b3);
                af[0][ks][j] = (short)a1;
                af[1][ks][j] = (short)a2;
                af[2][ks][j] = (short)a3;
            }
        }
        if (t + 1 < 16) {   // xv0 dead: prefetch next chunk (full-chunk window)
            const float* xp = xrow0 + (size_t)(t + 1) * 64;
            xv0[0] = *(const float4*)(xp);      xv0[1] = *(const float4*)(xp + 4);
            xv0[2] = *(const float4*)(xp + 32); xv0[3] = *(const float4*)(xp + 36);
        }
#pragma unroll
        for (int ks = 0; ks < 2; ++ks)
#pragma unroll
            for (int nt = 0; nt < 2; ++nt) {
                f32x4 t0 = acc0[ks][nt];
                t0 = __builtin_amdgcn_mfma_f32_16x16x32_bf16(af[0][ks], b[0][ks][nt], t0, 0, 0, 0);
                t0 = __builtin_amdgcn_mfma_f32_16x16x32_bf16(af[0][ks], b[1][ks][nt], t0, 0, 0, 0);
                t0 = __builtin_amdgcn_mfma_f32_16x16x32_bf16(af[1][ks], b[0][ks][nt], t0, 0, 0, 0);
                t0 = __builtin_amdgcn_mfma_f32_16x16x32_bf16(af[0][ks], b[2][ks][nt], t0, 0, 0, 0);
                t0 = __builtin_amdgcn_mfma_f32_16x16x32_bf16(af[2][ks], b[0][ks][nt], t0, 0, 0, 0);
                t0 = __builtin_amdgcn_mfma_f32_16x16x32_bf16(af[1][ks], b[1][ks][nt], t0, 0, 0, 0);
                acc0[ks][nt] = t0;
            }

        // ---------- token subgroup 1 (reuses the SAME b frags) ----------
#pragma unroll
        for (int ks = 0; ks < 2; ++ks) {
            const float xe[8] = {xv1[ks * 2].x,     xv1[ks * 2].y,
                                 xv1[ks * 2].z,     xv1[ks * 2].w,
                                 xv1[ks * 2 + 1].x, xv1[ks * 2 + 1].y,
                                 xv1[ks * 2 + 1].z, xv1[ks * 2 + 1].w};
#pragma unroll
            for (int j = 0; j < 8; ++j) {
                float b1, b2, b3;
                const u16 a1 = f2bf(xe[j], b1);
                const float d1 = xe[j] - b1;
                const u16 a2 = f2bf(d1, b2);
                const float d2 = d1 - b2;
                const u16 a3 = f2bf(d2, b3);
                af[0][ks][j] = (short)a1;
                af[1][ks][j] = (short)a2;
                af[2][ks][j] = (short)a3;
            }
        }
        if (t + 1 < 16) {
            const float* xp = xrow1 + (size_t)(t + 1) * 64;
            xv1[0] = *(const float4*)(xp);      xv1[1] = *(const float4*)(xp + 4);
            xv1[2] = *(const float4*)(xp + 32); xv1[3] = *(const float4*)(xp + 36);
        }
#pragma unroll
        for (int ks = 0; ks < 2; ++ks)
#pragma unroll
            for (int nt = 0; nt < 2; ++nt) {
                f32x4 t0 = acc1[ks][nt];
                t0 = __builtin_amdgcn_mfma_f32_16x16x32_bf16(af[0][ks], b[0][ks][nt], t0, 0, 0, 0);
                t0 = __builtin_amdgcn_mfma_f32_16x16x32_bf16(af[0][ks], b[1][ks][nt], t0, 0, 0, 0);
                t0 = __builtin_amdgcn_mfma_f32_16x16x32_bf16(af[1][ks], b[0][ks][nt], t0, 0, 0, 0);
                t0 = __builtin_amdgcn_mfma_f32_16x16x32_bf16(af[0][ks], b[2][ks][nt], t0, 0, 0, 0);
                t0 = __builtin_amdgcn_mfma_f32_16x16x32_bf16(af[2][ks], b[0][ks][nt], t0, 0, 0, 0);
                t0 = __builtin_amdgcn_mfma_f32_16x16x32_bf16(af[1][ks], b[1][ks][nt], t0, 0, 0, 0);
                acc1[ks][nt] = t0;
            }

        // fp64 flush once per 64-k chunk, both subgroups (identical per token)
#pragma unroll
        for (int nt = 0; nt < 2; ++nt)
#pragma unroll
            for (int r = 0; r < 4; ++r) {
                accd0[nt][r] += (double)acc0[0][nt][r] + (double)acc0[1][nt][r];
                acc0[0][nt][r] = 0.f;
                acc0[1][nt][r] = 0.f;
                accd1[nt][r] += (double)acc1[0][nt][r] + (double)acc1[1][nt][r];
                acc1[0][nt][r] = 0.f;
                acc1[1][nt][r] = 0.f;
            }
    }

    // epilogue: k-half exchange (ONE barrier in the whole kernel)
    // C/D mapping (m89): token row = (lane>>4)*4 + r, expert col = lane&15
#pragma unroll
    for (int nt = 0; nt < 2; ++nt)
#pragma unroll
        for (int r = 0; r < 4; ++r) {
            const int row = (lane >> 4) * 4 + r;
            const int col = eh * 32 + nt * 16 + (lane & 15);
            lg[kh][row][col]      = accd0[nt][r];
            lg[kh][row + 16][col] = accd1[nt][r];
        }
    __syncthreads();

    // fused top-8: wave handles 8 tokens, lane = expert (verified epilogue)
    const float be = bias[lane];
#pragma unroll 1
    for (int i = 0; i < 8; ++i) {
        const int tl = w * 8 + i;
        float v = (float)(lg[0][tl][lane] + lg[1][tl][lane]) + be;
        const int myi = lane;
        float bv = 0.0f; int bi = 0;
#pragma unroll
        for (int r = 0; r < TOPK; ++r) {
            float mv = v; int mi = myi;
#pragma unroll
            for (int off = 32; off > 0; off >>= 1) {
                const float ov = __shfl_xor(mv, off, 64);
                const int   oi = __shfl_xor(mi, off, 64);
                if (ov > mv || (ov == mv && oi < mi)) { mv = ov; mi = oi; }
            }
            if (lane == r) { bv = mv; bi = mi; }
            if (myi == mi) { v = -INFINITY; }
        }
        if (lane < TOPK) {
            const size_t tok = tokBase + tl;
            out_w[tok * TOPK + lane] = 1.0f / (1.0f + expf(-bv));
            out_i[tok * TOPK + lane] = (float)bi;
        }
    }
}

extern "C" void kernel_launch(void* const* d_in, const int* in_sizes, int n_in,
                              void* d_out, int out_size, void* d_ws, size_t ws_size,
                              hipStream_t stream) {
    const float* x    = (const float*)d_in[0];   // [4,4096,2048]
    const float* W    = (const float*)d_in[1];   // [64,2048]
    const float* bias = (const float*)d_in[2];   // [64]
    float* out_w = (float*)d_out;                          // [16384,8]
    float* out_i = (float*)d_out + (size_t)TOKENS * TOPK;  // [16384,8] as float
    u16* wimg = (u16*)d_ws;  // 32 * 24576 B = 786432 B, fragment-ordered

    wconv<<<dim3((NEXP * DMODEL / 8) / 256), 256, 0, stream>>>(W, wimg);
    router_fused<<<dim3(TOKENS / 32), 256, 0, stream>>>(x, wimg, bias, out_w, out_i);
}

// Round 14
// 250.760 us; speedup vs baseline: 1.0225x; 1.0197x over previous
//
#include <hip/hip_runtime.h>
#include <math.h>

#define TOKENS 16384
#define DMODEL 2048
#define NEXP   64
#define TOPK   8
#define WSHORTS 12288        // shorts per 64-k chunk W image (24 frags x 1024 B)
#define KSPLIT  16           // 128 k per block

typedef unsigned short u16;
typedef float f32x4 __attribute__((ext_vector_type(4)));
typedef short s16x8 __attribute__((ext_vector_type(8)));

// RNE fp32 -> bf16, also returning the rounded-back fp32 value.
// (bit-identical to all passing kernels' split)
__device__ __forceinline__ u16 f2bf(float f, float& back) {
    unsigned u = __float_as_uint(f);
    unsigned r = u + 0x7fffu + ((u >> 16) & 1u);
    back = __uint_as_float(r & 0xffff0000u);
    return (u16)(r >> 16);
}

// Kernel 1 (unchanged, passing since R2): pre-split W into 3 bf16 terms in
// MFMA B-FRAGMENT ORDER: chunk c -> 24 fragments of 1024B, frag(tau,ks,eq) at
// ((tau*2+ks)*4+eq), lane l's 16B = expert eq*16+(l&15), k=c*64+ks*32+(l>>4)*8.
__global__ __launch_bounds__(256) void wconv(
    const float* __restrict__ W, u16* __restrict__ wimg)
{
    const int id  = blockIdx.x * 256 + threadIdx.x;  // 16384 threads
    const int e   = id >> 8;     // expert 0..63
    const int ko8 = id & 255;    // k-oct 0..255
    const int k0  = ko8 * 8;
    const int c   = ko8 >> 3;          // chunk
    const int ks  = (ko8 >> 2) & 1;    // k-half within chunk
    const int hi  = ko8 & 3;           // lane>>4 part
    const int lane = hi * 16 + (e & 15);
    const int eq   = e >> 4;

    const float* src = W + (size_t)e * DMODEL + k0;
    const float4 f0 = *(const float4*)(src);
    const float4 f1 = *(const float4*)(src + 4);
    const float xe[8] = {f0.x, f0.y, f0.z, f0.w, f1.x, f1.y, f1.z, f1.w};
    s16x8 va, vb, vc;
#pragma unroll
    for (int j = 0; j < 8; ++j) {
        float b1, b2, b3;
        const u16 a1 = f2bf(xe[j], b1);
        const float d1 = xe[j] - b1;   // exact (Sterbenz)
        const u16 a2 = f2bf(d1, b2);
        const float d2 = d1 - b2;      // exact
        const u16 a3 = f2bf(d2, b3);
        va[j] = (short)a1; vb[j] = (short)a2; vc[j] = (short)a3;
    }
    u16* base = wimg + (size_t)c * WSHORTS + lane * 8;
    *(s16x8*)(base + ((0 * 2 + ks) * 4 + eq) * 512) = va;
    *(s16x8*)(base + ((1 * 2 + ks) * 4 + eq) * 512) = vb;
    *(s16x8*)(base + ((2 * 2 + ks) * 4 + eq) * 512) = vc;
}

// Kernel 2: split-K MFMA gemm with B staged in LDS ONCE per block.
//  R11 diagnosis (quantitative): per-chunk wall time across R2/R7/R10/R11
//  equals (#global loads per chunk) x ~900cy -- the compiler sinks every
//  prefetch to its use (VGPR 64-104 << pipeline budget), so each wave's
//  chunk is a serial latency chain that 2-4 waves/SIMD cannot cover.
//  Fix: no B global loads in the loop at all. ksplit=16 -> block's B
//  footprint = 2 chunks x 24 KB = 48 KB, staged once (one barrier,
//  amortized), read via conflict-free lane*16 ds_read_b128. Inner 32-k step
//  has only TWO x-loads; 4 waves/SIMD (512thr, 48KB -> 2 blocks/CU) cover
//  their latency even when sunk.
//  Numerics per 32-k chunk (f2bf split, 6-MFMA chain order, fp64 accumulate
//  of each 32-k fp32 result) identical to passing kernels; fp32 partial per
//  128 k + fp64 combine in reduce mirrors the R0-passing split-K scheme.
__global__ __launch_bounds__(512) void router_mfma(
    const float* __restrict__ x, const u16* __restrict__ wimg,
    float* __restrict__ part)
{
    __shared__ __align__(16) u16 Bls[2 * WSHORTS];   // 49152 B

    const int tid  = threadIdx.x;
    const int lane = tid & 63;
    const int w    = tid >> 6;        // wave 0..7 (token subrange)
    const int ksp  = blockIdx.y;      // 0..15: owns k [ksp*128, ksp*128+128)
    const size_t tokBase = (size_t)blockIdx.x * 512;

    // ---- stage this split's B image: 48 KB linear, once ----
    {
        const float4* src = (const float4*)(wimg + (size_t)ksp * 2 * WSHORTS);
        float4* dst = (float4*)Bls;
#pragma unroll
        for (int r = 0; r < 6; ++r)          // 3072 float4 / 512 threads
            dst[r * 512 + tid] = src[r * 512 + tid];
    }
    __syncthreads();

    const int hi = lane >> 4;   // k-oct within 32-k slice
    // lane owns token (lane&15) of each 16-token group
    const float* xw = x + (tokBase + (size_t)w * 64 + (lane & 15)) * DMODEL +
                      ksp * 128 + hi * 8;

#pragma unroll 1
    for (int tg = 0; tg < 4; ++tg) {         // 4 x 16 tokens per wave
        double accd[4][4];
#pragma unroll
        for (int nt = 0; nt < 4; ++nt)
#pragma unroll
            for (int r = 0; r < 4; ++r) accd[nt][r] = 0.0;

        for (int kc = 0; kc < 4; ++kc) {     // 4 x 32-k slices
            const float* xp = xw + (size_t)tg * 16 * DMODEL + kc * 32;
            const float4 a0 = *(const float4*)(xp);
            const float4 a1 = *(const float4*)(xp + 4);

            // split 8 x-values -> 3 bf16 A-fragments (bit-identical values)
            s16x8 af0, af1, af2;
            {
                const float xe[8] = {a0.x, a0.y, a0.z, a0.w,
                                     a1.x, a1.y, a1.z, a1.w};
#pragma unroll
                for (int j = 0; j < 8; ++j) {
                    float b1, b2, b3;
                    const u16 t1 = f2bf(xe[j], b1);
                    const float d1 = xe[j] - b1;
                    const u16 t2 = f2bf(d1, b2);
                    const float d2 = d1 - b2;
                    const u16 t3 = f2bf(d2, b3);
                    af0[j] = (short)t1; af1[j] = (short)t2; af2[j] = (short)t3;
                }
            }

            // B fragments from LDS: base folds chunk (kc>>1) and ks (kc&1);
            // frag (tau,nt) at +tau*4096 + nt*512 shorts. lane*8 shorts ->
            // canonical conflict-free b128 pattern.
            const u16* bb = Bls + (size_t)(kc >> 1) * WSHORTS +
                            (kc & 1) * 2048 + lane * 8;

#pragma unroll
            for (int nt = 0; nt < 4; ++nt) {
                const s16x8 b1 = *(const s16x8*)(bb + 0 * 4096 + nt * 512);
                const s16x8 b2 = *(const s16x8*)(bb + 1 * 4096 + nt * 512);
                const s16x8 b3 = *(const s16x8*)(bb + 2 * 4096 + nt * 512);
                f32x4 t0 = (f32x4){0.f, 0.f, 0.f, 0.f};
                t0 = __builtin_amdgcn_mfma_f32_16x16x32_bf16(af0, b1, t0, 0, 0, 0);
                t0 = __builtin_amdgcn_mfma_f32_16x16x32_bf16(af0, b2, t0, 0, 0, 0);
                t0 = __builtin_amdgcn_mfma_f32_16x16x32_bf16(af1, b1, t0, 0, 0, 0);
                t0 = __builtin_amdgcn_mfma_f32_16x16x32_bf16(af0, b3, t0, 0, 0, 0);
                t0 = __builtin_amdgcn_mfma_f32_16x16x32_bf16(af2, b1, t0, 0, 0, 0);
                t0 = __builtin_amdgcn_mfma_f32_16x16x32_bf16(af1, b2, t0, 0, 0, 0);
                // fp64 accumulate of this 32-k fp32 result (per-32k flush)
#pragma unroll
                for (int r = 0; r < 4; ++r) accd[nt][r] += (double)t0[r];
            }
        }

        // write fp32 partial. C/D mapping (m89): token row = hi*4+r,
        // expert col = nt*16 + (lane&15)
#pragma unroll
        for (int nt = 0; nt < 4; ++nt)
#pragma unroll
            for (int r = 0; r < 4; ++r) {
                const size_t tok = tokBase + w * 64 + tg * 16 + hi * 4 + r;
                part[((size_t)ksp * TOKENS + tok) * NEXP + nt * 16 +
                     (lane & 15)] = (float)accd[nt][r];
            }
    }
}

// Kernel 3: R0's verbatim-passing wave-per-token fused split-K reduce (fp64)
// + bias + top-8 + sigmoid.
__global__ __launch_bounds__(256) void router_reduce_topk(
    const float* __restrict__ part, const float* __restrict__ bias,
    float* __restrict__ out_w, float* __restrict__ out_i, int ksplit)
{
    const int lane = threadIdx.x & 63;
    const int wid  = threadIdx.x >> 6;
    const size_t t = (size_t)blockIdx.x * 4 + wid;

    double vd = (double)bias[lane];
    for (int kc = 0; kc < ksplit; ++kc)
        vd += (double)part[((size_t)kc * TOKENS + t) * NEXP + lane];
    float v = (float)vd;

    const int myi = lane;
    float bv = 0.0f; int bi = 0;
#pragma unroll
    for (int r = 0; r < TOPK; ++r) {
        float mv = v; int mi = myi;
#pragma unroll
        for (int off = 32; off > 0; off >>= 1) {
            const float ov = __shfl_xor(mv, off, 64);
            const int   oi = __shfl_xor(mi, off, 64);
            if (ov > mv || (ov == mv && oi < mi)) { mv = ov; mi = oi; }
        }
        if (lane == r)  { bv = mv; bi = mi; }
        if (myi == mi)  { v = -INFINITY; }
    }

    if (lane < TOPK) {
        out_w[t * TOPK + lane] = 1.0f / (1.0f + expf(-bv));
        out_i[t * TOPK + lane] = (float)bi;
    }
}

extern "C" void kernel_launch(void* const* d_in, const int* in_sizes, int n_in,
                              void* d_out, int out_size, void* d_ws, size_t ws_size,
                              hipStream_t stream) {
    const float* x    = (const float*)d_in[0];   // [4,4096,2048]
    const float* W    = (const float*)d_in[1];   // [64,2048]
    const float* bias = (const float*)d_in[2];   // [64]
    float* out_w = (float*)d_out;                          // [16384,8]
    float* out_i = (float*)d_out + (size_t)TOKENS * TOPK;  // [16384,8] as float
    u16*   wimg = (u16*)d_ws;                              // 768 KB frag image
    float* part = (float*)((char*)d_ws + (1 << 20));       // 16 x 4 MB partials

    wconv<<<dim3((NEXP * DMODEL / 8) / 256), 256, 0, stream>>>(W, wimg);
    router_mfma<<<dim3(TOKENS / 512, KSPLIT), 512, 0, stream>>>(x, wimg, part);
    router_reduce_topk<<<TOKENS / 4, 256, 0, stream>>>(part, bias, out_w, out_i,
                                                       KSPLIT);
}

// Round 15
// 238.392 us; speedup vs baseline: 1.0755x; 1.0519x over previous
//
#include <hip/hip_runtime.h>
#include <math.h>

#define TOKENS 16384
#define DMODEL 2048
#define NEXP   64
#define TOPK   8
#define WSHORTS 12288        // shorts per 64-k chunk W image (24 frags x 1024 B)
#define KSPLIT  16           // 128 k per block

typedef unsigned short u16;
typedef float f32x4 __attribute__((ext_vector_type(4)));
typedef short s16x8 __attribute__((ext_vector_type(8)));

// RNE fp32 -> bf16, also returning the rounded-back fp32 value.
// (bit-identical to all passing kernels' split)
__device__ __forceinline__ u16 f2bf(float f, float& back) {
    unsigned u = __float_as_uint(f);
    unsigned r = u + 0x7fffu + ((u >> 16) & 1u);
    back = __uint_as_float(r & 0xffff0000u);
    return (u16)(r >> 16);
}

// Kernel 1 (unchanged, passing since R2): pre-split W into 3 bf16 terms in
// MFMA B-FRAGMENT ORDER: chunk c -> 24 fragments of 1024B, frag(tau,ks,eq) at
// ((tau*2+ks)*4+eq), lane l's 16B = expert eq*16+(l&15), k=c*64+ks*32+(l>>4)*8.
__global__ __launch_bounds__(256) void wconv(
    const float* __restrict__ W, u16* __restrict__ wimg)
{
    const int id  = blockIdx.x * 256 + threadIdx.x;  // 16384 threads
    const int e   = id >> 8;     // expert 0..63
    const int ko8 = id & 255;    // k-oct 0..255
    const int k0  = ko8 * 8;
    const int c   = ko8 >> 3;          // chunk
    const int ks  = (ko8 >> 2) & 1;    // k-half within chunk
    const int hi  = ko8 & 3;           // lane>>4 part
    const int lane = hi * 16 + (e & 15);
    const int eq   = e >> 4;

    const float* src = W + (size_t)e * DMODEL + k0;
    const float4 f0 = *(const float4*)(src);
    const float4 f1 = *(const float4*)(src + 4);
    const float xe[8] = {f0.x, f0.y, f0.z, f0.w, f1.x, f1.y, f1.z, f1.w};
    s16x8 va, vb, vc;
#pragma unroll
    for (int j = 0; j < 8; ++j) {
        float b1, b2, b3;
        const u16 a1 = f2bf(xe[j], b1);
        const float d1 = xe[j] - b1;   // exact (Sterbenz)
        const u16 a2 = f2bf(d1, b2);
        const float d2 = d1 - b2;      // exact
        const u16 a3 = f2bf(d2, b3);
        va[j] = (short)a1; vb[j] = (short)a2; vc[j] = (short)a3;
    }
    u16* base = wimg + (size_t)c * WSHORTS + lane * 8;
    *(s16x8*)(base + ((0 * 2 + ks) * 4 + eq) * 512) = va;
    *(s16x8*)(base + ((1 * 2 + ks) * 4 + eq) * 512) = vb;
    *(s16x8*)(base + ((2 * 2 + ks) * 4 + eq) * 512) = vc;
}

// Kernel 2: R14's split-K LDS-B gemm + ENFORCED x software pipeline.
//  R14 counters: 92.9us, MfmaUtil 10.6, VALUBusy 16.7, 73% of cycles idle on
//  16 resident waves -> the sole remaining global op (x loads) is still
//  latency-exposed: the compiler sinks plain loads to first use (R2/R7
//  precedent). Fix: half-tg (2-kc) pipeline where the NEXT batch's 4 loads
//  are issued and PINNED with asm volatile("":::"memory") -- a load cannot
//  sink past a potential memory writer -- then the current batch's compute
//  (~700cy of split+ds_read+MFMA) runs before the loaded regs are consumed.
//  __launch_bounds__(512,4) pins VGPR<=128 so the in-flight batch can't tip
//  occupancy into the 8-wave tier.
//  Numerics byte-identical to passing R14: f2bf splits, 6-MFMA chain order,
//  fp64 accumulate of each 32-k fp32 result, fp32 partial per 128k.
__global__ __launch_bounds__(512, 4) void router_mfma(
    const float* __restrict__ x, const u16* __restrict__ wimg,
    float* __restrict__ part)
{
    __shared__ __align__(16) u16 Bls[2 * WSHORTS];   // 49152 B

    const int tid  = threadIdx.x;
    const int lane = tid & 63;
    const int w    = tid >> 6;        // wave 0..7 (token subrange)
    const int ksp  = blockIdx.y;      // 0..15: owns k [ksp*128, ksp*128+128)
    const size_t tokBase = (size_t)blockIdx.x * 512;

    // ---- stage this split's B image: 48 KB linear, once ----
    {
        const float4* src = (const float4*)(wimg + (size_t)ksp * 2 * WSHORTS);
        float4* dst = (float4*)Bls;
#pragma unroll
        for (int r = 0; r < 6; ++r)          // 3072 float4 / 512 threads
            dst[r * 512 + tid] = src[r * 512 + tid];
    }
    __syncthreads();

    const int hi = lane >> 4;   // k-oct within 32-k slice
    // lane owns token (lane&15) of each 16-token group
    const float* xw = x + (tokBase + (size_t)w * 64 + (lane & 15)) * DMODEL +
                      ksp * 128 + hi * 8;

    // ---- x pipeline: xc = current 2-kc batch, xn = in-flight next batch ----
    float4 xc[4], xn[4];
    {   // preload tg0 half A (kc 0,1)
        xc[0] = *(const float4*)(xw);
        xc[1] = *(const float4*)(xw + 4);
        xc[2] = *(const float4*)(xw + 32);
        xc[3] = *(const float4*)(xw + 36);
    }
    asm volatile("" ::: "memory");

    // one 2-kc compute batch from xc regs, accumulating into accd
#define COMPUTE_HALF(kcA)                                                     \
    {                                                                         \
        _Pragma("unroll") for (int kc2 = 0; kc2 < 2; ++kc2) {                 \
            const int kc = (kcA) + kc2;                                       \
            s16x8 af0, af1, af2;                                              \
            {                                                                 \
                const float4 a0 = xc[kc2 * 2], a1 = xc[kc2 * 2 + 1];          \
                const float xe[8] = {a0.x, a0.y, a0.z, a0.w,                  \
                                     a1.x, a1.y, a1.z, a1.w};                 \
                _Pragma("unroll") for (int j = 0; j < 8; ++j) {               \
                    float b1_, b2_, b3_;                                      \
                    const u16 t1 = f2bf(xe[j], b1_);                          \
                    const float d1 = xe[j] - b1_;                             \
                    const u16 t2 = f2bf(d1, b2_);                             \
                    const float d2 = d1 - b2_;                                \
                    const u16 t3 = f2bf(d2, b3_);                             \
                    af0[j] = (short)t1; af1[j] = (short)t2; af2[j] = (short)t3;\
                }                                                             \
            }                                                                 \
            const u16* bb = Bls + (size_t)(kc >> 1) * WSHORTS +               \
                            (kc & 1) * 2048 + lane * 8;                       \
            _Pragma("unroll") for (int nt = 0; nt < 4; ++nt) {                \
                const s16x8 b1 = *(const s16x8*)(bb + 0 * 4096 + nt * 512);   \
                const s16x8 b2 = *(const s16x8*)(bb + 1 * 4096 + nt * 512);   \
                const s16x8 b3 = *(const s16x8*)(bb + 2 * 4096 + nt * 512);   \
                f32x4 t0 = (f32x4){0.f, 0.f, 0.f, 0.f};                       \
                t0 = __builtin_amdgcn_mfma_f32_16x16x32_bf16(af0, b1, t0, 0, 0, 0); \
                t0 = __builtin_amdgcn_mfma_f32_16x16x32_bf16(af0, b2, t0, 0, 0, 0); \
                t0 = __builtin_amdgcn_mfma_f32_16x16x32_bf16(af1, b1, t0, 0, 0, 0); \
                t0 = __builtin_amdgcn_mfma_f32_16x16x32_bf16(af0, b3, t0, 0, 0, 0); \
                t0 = __builtin_amdgcn_mfma_f32_16x16x32_bf16(af2, b1, t0, 0, 0, 0); \
                t0 = __builtin_amdgcn_mfma_f32_16x16x32_bf16(af1, b2, t0, 0, 0, 0); \
                _Pragma("unroll") for (int r = 0; r < 4; ++r)                 \
                    accd[nt][r] += (double)t0[r];                             \
            }                                                                 \
        }                                                                     \
    }

#pragma unroll 1
    for (int tg = 0; tg < 4; ++tg) {
        double accd[4][4];
#pragma unroll
        for (int nt = 0; nt < 4; ++nt)
#pragma unroll
            for (int r = 0; r < 4; ++r) accd[nt][r] = 0.0;

        // ---- half A: issue loads for half B (this tg, kc 2,3), then compute
        {
            const float* xp = xw + (size_t)tg * 16 * DMODEL + 64;
            xn[0] = *(const float4*)(xp);
            xn[1] = *(const float4*)(xp + 4);
            xn[2] = *(const float4*)(xp + 32);
            xn[3] = *(const float4*)(xp + 36);
        }
        asm volatile("" ::: "memory");   // pin: loads issued before compute
        COMPUTE_HALF(0)
#pragma unroll
        for (int q = 0; q < 4; ++q) xc[q] = xn[q];

        // ---- half B: issue loads for next tg's half A, then compute
        if (tg + 1 < 4) {
            const float* xp = xw + (size_t)(tg + 1) * 16 * DMODEL;
            xn[0] = *(const float4*)(xp);
            xn[1] = *(const float4*)(xp + 4);
            xn[2] = *(const float4*)(xp + 32);
            xn[3] = *(const float4*)(xp + 36);
        }
        asm volatile("" ::: "memory");
        COMPUTE_HALF(2)
#pragma unroll
        for (int q = 0; q < 4; ++q) xc[q] = xn[q];

        // write fp32 partial. C/D mapping (m89): token row = hi*4+r,
        // expert col = nt*16 + (lane&15)
#pragma unroll
        for (int nt = 0; nt < 4; ++nt)
#pragma unroll
            for (int r = 0; r < 4; ++r) {
                const size_t tok = tokBase + w * 64 + tg * 16 + hi * 4 + r;
                part[((size_t)ksp * TOKENS + tok) * NEXP + nt * 16 +
                     (lane & 15)] = (float)accd[nt][r];
            }
    }
#undef COMPUTE_HALF
}

// Kernel 3: R0's verbatim-passing wave-per-token fused split-K reduce (fp64)
// + bias + top-8 + sigmoid.
__global__ __launch_bounds__(256) void router_reduce_topk(
    const float* __restrict__ part, const float* __restrict__ bias,
    float* __restrict__ out_w, float* __restrict__ out_i, int ksplit)
{
    const int lane = threadIdx.x & 63;
    const int wid  = threadIdx.x >> 6;
    const size_t t = (size_t)blockIdx.x * 4 + wid;

    double vd = (double)bias[lane];
    for (int kc = 0; kc < ksplit; ++kc)
        vd += (double)part[((size_t)kc * TOKENS + t) * NEXP + lane];
    float v = (float)vd;

    const int myi = lane;
    float bv = 0.0f; int bi = 0;
#pragma unroll
    for (int r = 0; r < TOPK; ++r) {
        float mv = v; int mi = myi;
#pragma unroll
        for (int off = 32; off > 0; off >>= 1) {
            const float ov = __shfl_xor(mv, off, 64);
            const int   oi = __shfl_xor(mi, off, 64);
            if (ov > mv || (ov == mv && oi < mi)) { mv = ov; mi = oi; }
        }
        if (lane == r)  { bv = mv; bi = mi; }
        if (myi == mi)  { v = -INFINITY; }
    }

    if (lane < TOPK) {
        out_w[t * TOPK + lane] = 1.0f / (1.0f + expf(-bv));
        out_i[t * TOPK + lane] = (float)bi;
    }
}

extern "C" void kernel_launch(void* const* d_in, const int* in_sizes, int n_in,
                              void* d_out, int out_size, void* d_ws, size_t ws_size,
                              hipStream_t stream) {
    const float* x    = (const float*)d_in[0];   // [4,4096,2048]
    const float* W    = (const float*)d_in[1];   // [64,2048]
    const float* bias = (const float*)d_in[2];   // [64]
    float* out_w = (float*)d_out;                          // [16384,8]
    float* out_i = (float*)d_out + (size_t)TOKENS * TOPK;  // [16384,8] as float
    u16*   wimg = (u16*)d_ws;                              // 768 KB frag image
    float* part = (float*)((char*)d_ws + (1 << 20));       // 16 x 4 MB partials

    wconv<<<dim3((NEXP * DMODEL / 8) / 256), 256, 0, stream>>>(W, wimg);
    router_mfma<<<dim3(TOKENS / 512, KSPLIT), 512, 0, stream>>>(x, wimg, part);
    router_reduce_topk<<<TOKENS / 4, 256, 0, stream>>>(part, bias, out_w, out_i,
                                                       KSPLIT);
}